// Round 1
// baseline (47.931 us; speedup 1.0000x reference)
//
#include <hip/hip_runtime.h>

typedef __attribute__((ext_vector_type(8))) short short8;
typedef __attribute__((ext_vector_type(4))) float f32x4;

static __device__ inline unsigned short f2bf(float x) {
    unsigned int u = __float_as_uint(x);
    u = (u + 0x7FFFu + ((u >> 16) & 1u)) >> 16;
    return (unsigned short)u;
}

// ---------------- Kernel 1: L2-normalize rows, cast to bf16 ----------------
// grid 3072 x 256; one wave per 128-elem row. rows [0,4096) -> f, [4096,12288) -> g
__global__ __launch_bounds__(256) void knorm(const float* __restrict__ feats,
                                             const float* __restrict__ nfeats,
                                             unsigned short* __restrict__ fb,
                                             unsigned short* __restrict__ gb) {
    int row = blockIdx.x * 4 + (threadIdx.x >> 6);
    int lane = threadIdx.x & 63;
    const float* src;
    unsigned short* dst;
    if (row < 4096) { src = feats + row * 128;          dst = fb + row * 128; }
    else            { src = nfeats + (row - 4096) * 128; dst = gb + (row - 4096) * 128; }
    float2 v = ((const float2*)src)[lane];
    float ss = v.x * v.x + v.y * v.y;
    #pragma unroll
    for (int d = 32; d; d >>= 1) ss += __shfl_xor(ss, d);
    float inv = 1.0f / sqrtf(ss);
    ushort2 o;
    o.x = f2bf(v.x * inv);
    o.y = f2bf(v.y * inv);
    ((ushort2*)dst)[lane] = o;
}

// ---------------- Kernel 2: max_q dot(f[p], g[q]) via MFMA ----------------
// grid (8 ptile, 8 m, 4 n), 256 thr = 4 waves; wave owns 32 p rows.
__global__ __launch_bounds__(256) void kscore(const unsigned short* __restrict__ fb,
                                              const unsigned short* __restrict__ gb,
                                              const float* __restrict__ mask,
                                              float* __restrict__ sp_patch) {
    __shared__ unsigned short gtile[2][32 * 128];  // 2 x 8KB, XOR-swizzled rows
    const int tid = threadIdx.x;
    const int lane = tid & 63;
    const int wave = tid >> 6;
    const int l15 = lane & 15, lhi = lane >> 4;
    const int n = blockIdx.z, m = blockIdx.y;
    const int pbase = blockIdx.x * 128 + wave * 32;

    // A fragments in registers: 2 p-groups x 4 k-groups, 8 bf16 each
    short8 a[2][4];
    #pragma unroll
    for (int pg = 0; pg < 2; pg++) {
        const unsigned short* arow = fb + (size_t)(n * 1024 + pbase + pg * 16 + l15) * 128;
        #pragma unroll
        for (int kk = 0; kk < 4; kk++)
            a[pg][kk] = *(const short8*)(arow + kk * 32 + lhi * 8);
    }

    f32x4 mx[2];
    #pragma unroll
    for (int i = 0; i < 4; i++) { mx[0][i] = -1e30f; mx[1][i] = -1e30f; }

    const unsigned short* gBase = gb + (size_t)m * 1024 * 128;

    auto stage = [&](int buf, int qb) {
        #pragma unroll
        for (int c = tid; c < 512; c += 256) {
            int row = c >> 4, col = c & 15;
            short8 v = *(const short8*)(gBase + (size_t)(qb + row) * 128 + col * 8);
            int addr = (row * 256 + col * 16) ^ ((row & 7) << 4);
            *(short8*)((char*)gtile[buf] + addr) = v;
        }
    };

    stage(0, 0);
    __syncthreads();
    int buf = 0;
    for (int qb = 0; qb < 1024; qb += 32) {
        if (qb + 32 < 1024) stage(buf ^ 1, qb + 32);
        const char* tp = (const char*)gtile[buf];
        #pragma unroll
        for (int qt = 0; qt < 2; qt++) {
            int r = qt * 16 + l15;
            int rowoff = r * 256;
            int swz = (r & 7) << 4;
            f32x4 acc0 = {0.f, 0.f, 0.f, 0.f};
            f32x4 acc1 = {0.f, 0.f, 0.f, 0.f};
            #pragma unroll
            for (int kk = 0; kk < 4; kk++) {
                short8 b = *(const short8*)(tp + ((rowoff + kk * 64 + lhi * 16) ^ swz));
                acc0 = __builtin_amdgcn_mfma_f32_16x16x32_bf16(a[0][kk], b, acc0, 0, 0, 0);
                acc1 = __builtin_amdgcn_mfma_f32_16x16x32_bf16(a[1][kk], b, acc1, 0, 0, 0);
            }
            #pragma unroll
            for (int i = 0; i < 4; i++) {
                mx[0][i] = fmaxf(mx[0][i], acc0[i]);
                mx[1][i] = fmaxf(mx[1][i], acc1[i]);
            }
        }
        __syncthreads();
        buf ^= 1;
    }

    // reduce max over the 16 D-columns (q) = low 4 lane bits
    #pragma unroll
    for (int pg = 0; pg < 2; pg++)
        #pragma unroll
        for (int i = 0; i < 4; i++) {
            float v = mx[pg][i];
            v = fmaxf(v, __shfl_xor(v, 1));
            v = fmaxf(v, __shfl_xor(v, 2));
            v = fmaxf(v, __shfl_xor(v, 4));
            v = fmaxf(v, __shfl_xor(v, 8));
            mx[pg][i] = v;
        }
    if (l15 == 0) {
        #pragma unroll
        for (int pg = 0; pg < 2; pg++)
            #pragma unroll
            for (int i = 0; i < 4; i++) {
                int p = pbase + pg * 16 + lhi * 4 + i;
                float d = sqrtf(fmaxf(2.0f - 2.0f * mx[pg][i], 0.0f)) * 0.5f * mask[n * 1024 + p];
                sp_patch[(size_t)(n * 8 + m) * 1024 + p] = d;
            }
    }
}

// ---------------- Kernel 3: scores[n] = mean_m max_p ; sp_mean = mean_m ----
__global__ __launch_bounds__(256) void kreduce(const float* __restrict__ sp_patch,
                                               float* __restrict__ sp_mean,
                                               float* __restrict__ scores) {
    int n = blockIdx.x, t = threadIdx.x;
    __shared__ float smax[4];
    float sums[4] = {0.f, 0.f, 0.f, 0.f};
    float scoresum = 0.f;
    for (int m = 0; m < 8; m++) {
        float lm = -1e30f;
        #pragma unroll
        for (int i = 0; i < 4; i++) {
            float v = sp_patch[(size_t)(n * 8 + m) * 1024 + i * 256 + t];
            sums[i] += v;
            lm = fmaxf(lm, v);
        }
        #pragma unroll
        for (int d = 32; d; d >>= 1) lm = fmaxf(lm, __shfl_xor(lm, d));
        if ((t & 63) == 0) smax[t >> 6] = lm;
        __syncthreads();
        if (t == 0) scoresum += fmaxf(fmaxf(smax[0], smax[1]), fmaxf(smax[2], smax[3]));
        __syncthreads();
    }
    if (t == 0) scores[n] = scoresum * 0.125f;
    #pragma unroll
    for (int i = 0; i < 4; i++) sp_mean[n * 1024 + i * 256 + t] = sums[i] * 0.125f;
}

// ---------------- Kernel 4: bilinear 32x32 -> 512x512 (half-pixel, clamp) --
__global__ __launch_bounds__(256) void kupsample(const float* __restrict__ sp_mean,
                                                 float* __restrict__ outp) {
    int n = blockIdx.y;
    int idx = blockIdx.x * 256 + threadIdx.x;
    int y = idx >> 9, x = idx & 511;
    float fy = (y + 0.5f) * 0.0625f - 0.5f;
    float fx = (x + 0.5f) * 0.0625f - 0.5f;
    float yf = floorf(fy), xf = floorf(fx);
    float ty = fy - yf, tx = fx - xf;
    int y0 = (int)yf, x0 = (int)xf;
    int y0c = min(max(y0, 0), 31), y1c = min(max(y0 + 1, 0), 31);
    int x0c = min(max(x0, 0), 31), x1c = min(max(x0 + 1, 0), 31);
    const float* s = sp_mean + n * 1024;
    float v00 = s[y0c * 32 + x0c], v01 = s[y0c * 32 + x1c];
    float v10 = s[y1c * 32 + x0c], v11 = s[y1c * 32 + x1c];
    float v0 = v00 + tx * (v01 - v00);
    float v1 = v10 + tx * (v11 - v10);
    outp[(size_t)n * 262144 + idx] = v0 + ty * (v1 - v0);
}

extern "C" void kernel_launch(void* const* d_in, const int* in_sizes, int n_in,
                              void* d_out, int out_size, void* d_ws, size_t ws_size,
                              hipStream_t stream) {
    const float* feats = (const float*)d_in[0];           // [4,1024,128] f32
    const float* nfeats = (const float*)d_in[1];          // [8,1024,128] f32
    const float* mask = (const float*)d_in[2];            // [4,1024] f32
    float* out = (float*)d_out;                           // [4] scores + [4,512,512] pixel

    unsigned short* fb = (unsigned short*)d_ws;                         // 1 MB
    unsigned short* gb = fb + 4096 * 128;                               // 2 MB
    float* sp_patch = (float*)((char*)d_ws + 3u * 1024u * 1024u);       // 128 KB
    float* sp_mean = sp_patch + 4 * 8 * 1024;                           // 16 KB

    knorm<<<3072, 256, 0, stream>>>(feats, nfeats, fb, gb);
    kscore<<<dim3(8, 8, 4), 256, 0, stream>>>(fb, gb, mask, sp_patch);
    kreduce<<<4, 256, 0, stream>>>(sp_patch, sp_mean, out);
    kupsample<<<dim3(1024, 4), 256, 0, stream>>>(sp_mean, out + 4);
}

// Round 2
// 32.759 us; speedup vs baseline: 1.4632x; 1.4632x over previous
//
#include <hip/hip_runtime.h>

typedef __attribute__((ext_vector_type(8))) short short8;
typedef __attribute__((ext_vector_type(4))) float f32x4;

typedef const __attribute__((address_space(1))) unsigned int glb_u32;
typedef __attribute__((address_space(3))) unsigned int lds_u32;

static __device__ inline unsigned short f2bf(float x) {
    unsigned int u = __float_as_uint(x);
    u = (u + 0x7FFFu + ((u >> 16) & 1u)) >> 16;
    return (unsigned short)u;
}

// ---------------- Kernel 1: L2-normalize rows, cast to bf16 ----------------
// one wave per 128-elem row; rows [0,4096) -> f, [4096,12288) -> g
__global__ __launch_bounds__(256) void knorm(const float* __restrict__ feats,
                                             const float* __restrict__ nfeats,
                                             unsigned short* __restrict__ fb,
                                             unsigned short* __restrict__ gb) {
    int row = blockIdx.x * 4 + (threadIdx.x >> 6);
    int lane = threadIdx.x & 63;
    const float* src;
    unsigned short* dst;
    if (row < 4096) { src = feats + row * 128;           dst = fb + row * 128; }
    else            { src = nfeats + (row - 4096) * 128; dst = gb + (row - 4096) * 128; }
    float2 v = ((const float2*)src)[lane];
    float ss = v.x * v.x + v.y * v.y;
    #pragma unroll
    for (int d = 32; d; d >>= 1) ss += __shfl_xor(ss, d);
    float inv = 1.0f / sqrtf(ss);
    ushort2 o;
    o.x = f2bf(v.x * inv);
    o.y = f2bf(v.y * inv);
    ((ushort2*)dst)[lane] = o;
}

// ---------------- Kernel 2: partial max_q dot(f[p], g[q]) via MFMA ----------
// grid (4 ptile, 32 = m*4+qc, 4 n), 512 thr = 8 waves; wave owns 32 p rows.
// Each block covers 256 p x 256 q (one q-chunk of one m); writes raw dot-max.
__global__ __launch_bounds__(512, 4) void kscore(const unsigned short* __restrict__ fb,
                                                 const unsigned short* __restrict__ gb,
                                                 float* __restrict__ sp_part) {
    __shared__ unsigned short gtile[2][64 * 128];  // 2 x 16KB, XOR-swizzled image
    const int tid = threadIdx.x;
    const int lane = tid & 63;
    const int wave = tid >> 6;             // 0..7
    const int l15 = lane & 15, lhi = lane >> 4;
    const int n = blockIdx.z;
    const int m = blockIdx.y >> 2, qc = blockIdx.y & 3;
    const int pbase = blockIdx.x * 256 + wave * 32;

    // A fragments in registers: 2 p-groups x 4 k-groups, 8 bf16 each (64 VGPR)
    short8 a[2][4];
    #pragma unroll
    for (int pg = 0; pg < 2; pg++) {
        const unsigned short* arow = fb + (size_t)(n * 1024 + pbase + pg * 16 + l15) * 128;
        #pragma unroll
        for (int kk = 0; kk < 4; kk++)
            a[pg][kk] = *(const short8*)(arow + kk * 32 + lhi * 8);
    }

    f32x4 mx[2];
    #pragma unroll
    for (int i = 0; i < 4; i++) { mx[0][i] = -1e30f; mx[1][i] = -1e30f; }

    const unsigned short* gBase = gb + ((size_t)m * 1024 + qc * 256) * 128;

    // async global->LDS stage of 64 q rows; linear LDS dest, source column
    // pre-permuted so the LDS image matches addr=(r*256+col*16)^((r&7)<<4)
    auto stage = [&](int buf, int qb) {
        #pragma unroll
        for (int c = tid; c < 1024; c += 512) {
            int r = c >> 4, s = c & 15;
            int scol = s ^ (r & 7);
            __builtin_amdgcn_global_load_lds(
                (glb_u32*)(gBase + (size_t)(qb + r) * 128 + scol * 8),
                (lds_u32*)((char*)gtile[buf] + c * 16), 16, 0, 0);
        }
    };

    stage(0, 0);
    __syncthreads();
    int buf = 0;
    #pragma unroll
    for (int it = 0; it < 4; it++) {
        if (it < 3) stage(buf ^ 1, (it + 1) * 64);   // async, drains at barrier
        const char* tp = (const char*)gtile[buf];
        #pragma unroll
        for (int qt = 0; qt < 4; qt++) {
            int r = qt * 16 + l15;
            int rowoff = r * 256;
            int swz = (r & 7) << 4;
            f32x4 acc0 = {0.f, 0.f, 0.f, 0.f};
            f32x4 acc1 = {0.f, 0.f, 0.f, 0.f};
            #pragma unroll
            for (int kk = 0; kk < 4; kk++) {
                short8 b = *(const short8*)(tp + ((rowoff + kk * 64 + lhi * 16) ^ swz));
                acc0 = __builtin_amdgcn_mfma_f32_16x16x32_bf16(a[0][kk], b, acc0, 0, 0, 0);
                acc1 = __builtin_amdgcn_mfma_f32_16x16x32_bf16(a[1][kk], b, acc1, 0, 0, 0);
            }
            #pragma unroll
            for (int i = 0; i < 4; i++) {
                mx[0][i] = fmaxf(mx[0][i], acc0[i]);
                mx[1][i] = fmaxf(mx[1][i], acc1[i]);
            }
        }
        __syncthreads();
        buf ^= 1;
    }

    // reduce max over the 16 q-columns (C/D col = lane&15)
    #pragma unroll
    for (int pg = 0; pg < 2; pg++)
        #pragma unroll
        for (int i = 0; i < 4; i++) {
            float v = mx[pg][i];
            v = fmaxf(v, __shfl_xor(v, 1));
            v = fmaxf(v, __shfl_xor(v, 2));
            v = fmaxf(v, __shfl_xor(v, 4));
            v = fmaxf(v, __shfl_xor(v, 8));
            mx[pg][i] = v;
        }
    if (l15 == 0) {
        float* dst = sp_part + ((size_t)(n * 8 + m) * 4 + qc) * 1024;
        #pragma unroll
        for (int pg = 0; pg < 2; pg++)
            #pragma unroll
            for (int i = 0; i < 4; i++)
                dst[pbase + pg * 16 + lhi * 4 + i] = mx[pg][i];
    }
}

// ------- Kernel 3: fold qc, dot->dist, mask; scores[n] + sp_mean[n][p] ------
__global__ __launch_bounds__(256) void kreduce(const float* __restrict__ sp_part,
                                               const float* __restrict__ mask,
                                               float* __restrict__ sp_mean,
                                               float* __restrict__ scores) {
    int n = blockIdx.x, t = threadIdx.x;
    __shared__ float smax[4];
    float sums[4] = {0.f, 0.f, 0.f, 0.f};
    float scoresum = 0.f;
    for (int m = 0; m < 8; m++) {
        const float* base = sp_part + (size_t)(n * 8 + m) * 4 * 1024;
        float lm = -1e30f;
        #pragma unroll
        for (int i = 0; i < 4; i++) {
            int p = i * 256 + t;
            float dot = fmaxf(fmaxf(base[p], base[1024 + p]),
                              fmaxf(base[2048 + p], base[3072 + p]));
            float d = sqrtf(fmaxf(2.0f - 2.0f * dot, 0.0f)) * 0.5f * mask[n * 1024 + p];
            sums[i] += d;
            lm = fmaxf(lm, d);
        }
        #pragma unroll
        for (int d = 32; d; d >>= 1) lm = fmaxf(lm, __shfl_xor(lm, d));
        if ((t & 63) == 0) smax[t >> 6] = lm;
        __syncthreads();
        if (t == 0) scoresum += fmaxf(fmaxf(smax[0], smax[1]), fmaxf(smax[2], smax[3]));
        __syncthreads();
    }
    if (t == 0) scores[n] = scoresum * 0.125f;
    #pragma unroll
    for (int i = 0; i < 4; i++) sp_mean[n * 1024 + i * 256 + t] = sums[i] * 0.125f;
}

// ---------------- Kernel 4: bilinear 32x32 -> 512x512 (half-pixel, clamp) --
__global__ __launch_bounds__(256) void kupsample(const float* __restrict__ sp_mean,
                                                 float* __restrict__ outp) {
    int n = blockIdx.y;
    int idx = blockIdx.x * 256 + threadIdx.x;
    int y = idx >> 9, x = idx & 511;
    float fy = (y + 0.5f) * 0.0625f - 0.5f;
    float fx = (x + 0.5f) * 0.0625f - 0.5f;
    float yf = floorf(fy), xf = floorf(fx);
    float ty = fy - yf, tx = fx - xf;
    int y0 = (int)yf, x0 = (int)xf;
    int y0c = min(max(y0, 0), 31), y1c = min(max(y0 + 1, 0), 31);
    int x0c = min(max(x0, 0), 31), x1c = min(max(x0 + 1, 0), 31);
    const float* s = sp_mean + n * 1024;
    float v00 = s[y0c * 32 + x0c], v01 = s[y0c * 32 + x1c];
    float v10 = s[y1c * 32 + x0c], v11 = s[y1c * 32 + x1c];
    float v0 = v00 + tx * (v01 - v00);
    float v1 = v10 + tx * (v11 - v10);
    outp[(size_t)n * 262144 + idx] = v0 + ty * (v1 - v0);
}

extern "C" void kernel_launch(void* const* d_in, const int* in_sizes, int n_in,
                              void* d_out, int out_size, void* d_ws, size_t ws_size,
                              hipStream_t stream) {
    const float* feats = (const float*)d_in[0];           // [4,1024,128] f32
    const float* nfeats = (const float*)d_in[1];          // [8,1024,128] f32
    const float* mask = (const float*)d_in[2];            // [4,1024] f32
    float* out = (float*)d_out;                           // [4] scores + [4,512,512]

    unsigned short* fb = (unsigned short*)d_ws;                         // 1 MB
    unsigned short* gb = fb + 4096 * 128;                               // 2 MB
    float* sp_part = (float*)((char*)d_ws + 3u * 1024u * 1024u);        // 512 KB
    float* sp_mean = sp_part + 4 * 8 * 4 * 1024;                        // 16 KB

    knorm<<<3072, 256, 0, stream>>>(feats, nfeats, fb, gb);
    kscore<<<dim3(4, 32, 4), 512, 0, stream>>>(fb, gb, sp_part);
    kreduce<<<4, 256, 0, stream>>>(sp_part, mask, sp_mean, out);
    kupsample<<<dim3(1024, 4), 256, 0, stream>>>(sp_mean, out + 4);
}